// Round 1
// baseline (7892.916 us; speedup 1.0000x reference)
//
#include <hip/hip_runtime.h>
#include <hip/hip_bf16.h>

// Problem constants (from reference setup_inputs)
#define NVOX   4096   // B voxels
#define NMEAS  256    // M measurements
#define NATOMS 512    // K atoms
#define NITER  30

// g(v) = relu(v-0.1) - min(v,0.1)   (z - u collapsed through v = x + u)
__device__ __forceinline__ float g_of(float v) {
    return fmaxf(v - 0.1f, 0.0f) - fminf(v, 0.1f);
}

// ---------------------------------------------------------------------------
// K0: G = I + A * A^T   (A is [256][512] row-major, G [256][256])
// ---------------------------------------------------------------------------
__global__ __launch_bounds__(256) void g_kernel(const float* __restrict__ A,
                                                float* __restrict__ G) {
    __shared__ float arow[NATOMS];
    int i = blockIdx.x;
    for (int k = threadIdx.x; k < NATOMS; k += 256) arow[k] = A[i * NATOMS + k];
    __syncthreads();
    int j = threadIdx.x;
    const float* aj = A + j * NATOMS;
    float s = (i == j) ? 1.0f : 0.0f;
#pragma unroll 8
    for (int k = 0; k < NATOMS; ++k) s += arow[k] * aj[k];
    G[i * NMEAS + j] = s;
}

// ---------------------------------------------------------------------------
// K1: in-place Gauss-Jordan inverse of G (256x256 SPD, no pivoting needed).
// Single block, 1024 threads; whole matrix lives in registers (64 vals/thread).
// thread t: column c = t&255, rows r = (t>>8) + 4k, k=0..63
// ---------------------------------------------------------------------------
__global__ __launch_bounds__(1024) void gj_inverse(float* __restrict__ M) {
    __shared__ float s_prow[NMEAS];
    __shared__ float s_dums[NMEAS];
    int t = threadIdx.x;
    int c = t & 255;
    int r0 = t >> 8;
    float vals[64];
#pragma unroll
    for (int k = 0; k < 64; ++k) vals[k] = M[(r0 + 4 * k) * NMEAS + c];

#pragma unroll 1
    for (int p = 0; p < NMEAS; ++p) {
        __syncthreads();
        if (c == p) {
#pragma unroll
            for (int k = 0; k < 64; ++k) s_dums[r0 + 4 * k] = vals[k];
        }
        if (r0 == (p & 3)) s_prow[c] = vals[p >> 2];
        __syncthreads();
        float pivinv = 1.0f / s_prow[p];
        float pv = (c == p) ? pivinv : s_prow[c] * pivinv;  // scaled pivot row elem
#pragma unroll
        for (int k = 0; k < 64; ++k) {
            int r = r0 + 4 * k;
            float old = (c == p) ? 0.0f : vals[k];   // pivot column treated as 0
            float nv = old - s_dums[r] * pv;
            if (r == p) nv = pv;                      // pivot row <- scaled row
            vals[k] = nv;
        }
    }
#pragma unroll
    for (int k = 0; k < 64; ++k) M[(r0 + 4 * k) * NMEAS + c] = vals[k];
}

// ---------------------------------------------------------------------------
// K2: H = Ginv @ A   ([256][256] @ [256][512] -> [256][512])
// ---------------------------------------------------------------------------
__global__ __launch_bounds__(256) void h_kernel(const float* __restrict__ Gi,
                                                const float* __restrict__ A,
                                                float* __restrict__ H) {
    __shared__ float grow[NMEAS];
    int i = blockIdx.x;
    grow[threadIdx.x] = Gi[i * NMEAS + threadIdx.x];
    __syncthreads();
    int k0 = threadIdx.x;
    float s0 = 0.f, s1 = 0.f;
#pragma unroll 4
    for (int j = 0; j < NMEAS; ++j) {
        float g = grow[j];
        s0 += g * A[j * NATOMS + k0];
        s1 += g * A[j * NATOMS + k0 + 256];
    }
    H[i * NATOMS + k0] = s0;
    H[i * NATOMS + k0 + 256] = s1;
}

// ---------------------------------------------------------------------------
// K3: W = I - A^T @ H   ([512][256] @ [256][512] -> [512][512])
// ---------------------------------------------------------------------------
__global__ __launch_bounds__(256) void w_kernel(const float* __restrict__ A,
                                                const float* __restrict__ H,
                                                float* __restrict__ W) {
    __shared__ float acol[NMEAS];
    int p = blockIdx.x;
    acol[threadIdx.x] = A[threadIdx.x * NATOMS + p];
    __syncthreads();
    int q0 = threadIdx.x;
    float s0 = 0.f, s1 = 0.f;
#pragma unroll 4
    for (int m = 0; m < NMEAS; ++m) {
        float a = acol[m];
        s0 += a * H[m * NATOMS + q0];
        s1 += a * H[m * NATOMS + q0 + 256];
    }
    W[p * NATOMS + q0]       = ((p == q0)       ? 1.0f : 0.0f) - s0;
    W[p * NATOMS + q0 + 256] = ((p == q0 + 256) ? 1.0f : 0.0f) - s1;
}

// ---------------------------------------------------------------------------
// K4: AtY[k][b] = sum_m A[m][k] * Y[b][m]   -> [512][4096]
// tiled 64(k) x 64(b), K-chunks of 64 over m
// ---------------------------------------------------------------------------
__global__ __launch_bounds__(256) void aty_kernel(const float* __restrict__ A,
                                                  const float* __restrict__ Y,
                                                  float* __restrict__ AtY) {
    __shared__ __align__(16) float At[64][65];  // [m][k]
    __shared__ __align__(16) float Yt[64][65];  // [m][b]
    int b0 = blockIdx.x * 64, k0 = blockIdx.y * 64;
    int t = threadIdx.x, tx = t & 15, ty = t >> 4;
    float acc[4][4] = {};
    for (int m0 = 0; m0 < NMEAS; m0 += 64) {
        __syncthreads();
        {
            int kk = t & 63, mr = t >> 6;
#pragma unroll
            for (int p = 0; p < 16; ++p)
                At[mr + 4 * p][kk] = A[(m0 + mr + 4 * p) * NATOMS + k0 + kk];
            int mm = t & 63, br = t >> 6;
#pragma unroll
            for (int p = 0; p < 16; ++p)
                Yt[mm][br + 4 * p] = Y[(b0 + br + 4 * p) * NMEAS + m0 + mm];
        }
        __syncthreads();
#pragma unroll 4
        for (int m = 0; m < 64; ++m) {
            float av[4], yv[4];
#pragma unroll
            for (int i = 0; i < 4; ++i) av[i] = At[m][ty * 4 + i];
#pragma unroll
            for (int j = 0; j < 4; ++j) yv[j] = Yt[m][tx * 4 + j];
#pragma unroll
            for (int i = 0; i < 4; ++i)
#pragma unroll
                for (int j = 0; j < 4; ++j) acc[i][j] += av[i] * yv[j];
        }
    }
#pragma unroll
    for (int i = 0; i < 4; ++i) {
        int k = k0 + ty * 4 + i;
#pragma unroll
        for (int j = 0; j < 4; ++j)
            AtY[k * NVOX + b0 + tx * 4 + j] = acc[i][j];
    }
}

// ---------------------------------------------------------------------------
// K5: one ADMM iteration, fused:  x = W @ (AtY + g(vin)),
//     vout = x + min(vin, 0.1)     (or out[b][k] = x on LAST)
// C[512][4096] = W[512][512] @ T[512][4096], BM=64 BN=128 BK=32, 512 thr
// ---------------------------------------------------------------------------
template <int FIRST, int LAST>
__global__ __launch_bounds__(512) void admm_iter(const float* __restrict__ W,
                                                 const float* __restrict__ AtY,
                                                 const float* __restrict__ vin,
                                                 float* __restrict__ vout,
                                                 float* __restrict__ out) {
    __shared__ __align__(16) float Ws[64][33];
    __shared__ __align__(16) float Ts[32][132];
    int t = threadIdx.x;
    int tx = t & 31, ty = t >> 5;          // tx: n quad, ty: m quad
    int n0 = blockIdx.x * 128, m0 = blockIdx.y * 64;
    float acc[4][4] = {};

    for (int k0 = 0; k0 < NATOMS; k0 += 32) {
        __syncthreads();
        {   // stage W tile 64x32 (row-major, pitch 33)
            int c = t & 31, r4 = t >> 5;
#pragma unroll
            for (int p = 0; p < 4; ++p)
                Ws[r4 + 16 * p][c] = W[(m0 + r4 + 16 * p) * NATOMS + k0 + c];
            // stage T tile 32x128, computing t = AtY + g(v) on the fly
            int cc = t & 127, rr = t >> 7;
#pragma unroll
            for (int p = 0; p < 8; ++p) {
                int row = rr + 4 * p;
                int gi = (k0 + row) * NVOX + n0 + cc;
                float a = AtY[gi];
                if (!FIRST) a += g_of(vin[gi]);
                Ts[row][cc] = a;
            }
        }
        __syncthreads();
#pragma unroll 8
        for (int kk = 0; kk < 32; ++kk) {
            float4 tv = *(const float4*)&Ts[kk][tx * 4];
#pragma unroll
            for (int i = 0; i < 4; ++i) {
                float wv = Ws[ty * 4 + i][kk];
                acc[i][0] += wv * tv.x;
                acc[i][1] += wv * tv.y;
                acc[i][2] += wv * tv.z;
                acc[i][3] += wv * tv.w;
            }
        }
    }

    int n = n0 + tx * 4;
#pragma unroll
    for (int i = 0; i < 4; ++i) {
        int m = m0 + ty * 4 + i;
        if (LAST) {
            // final x written transposed: out[b][k] = x[k][b]
#pragma unroll
            for (int j = 0; j < 4; ++j) out[(n + j) * NATOMS + m] = acc[i][j];
        } else {
            float4 res;
            if (!FIRST) {
                float4 v = *(const float4*)&vin[m * NVOX + n];
                res.x = acc[i][0] + fminf(v.x, 0.1f);
                res.y = acc[i][1] + fminf(v.y, 0.1f);
                res.z = acc[i][2] + fminf(v.z, 0.1f);
                res.w = acc[i][3] + fminf(v.w, 0.1f);
            } else {
                res.x = acc[i][0]; res.y = acc[i][1];
                res.z = acc[i][2]; res.w = acc[i][3];
            }
            *(float4*)&vout[m * NVOX + n] = res;
        }
    }
}

// ---------------------------------------------------------------------------
extern "C" void kernel_launch(void* const* d_in, const int* in_sizes, int n_in,
                              void* d_out, int out_size, void* d_ws, size_t ws_size,
                              hipStream_t stream) {
    const float* Y = (const float*)d_in[0];   // [4096][256]
    const float* A = (const float*)d_in[1];   // [256][512]
    // d_in[2] = max_iter (=30, hardcoded; device-side scalar not host-readable)

    float* ws = (float*)d_ws;
    float* G   = ws;                      // 256*256      = 65536
    float* H   = ws + 65536;              // 256*512      = 131072
    float* Wm  = ws + 196608;             // 512*512      = 262144
    float* AtY = ws + 458752;             // 512*4096     = 2097152
    float* vA  = ws + 2555904;            // 512*4096     = 2097152
    float* vB  = (float*)d_out;           // scratch for even iterations

    g_kernel<<<256, 256, 0, stream>>>(A, G);
    gj_inverse<<<1, 1024, 0, stream>>>(G);
    h_kernel<<<256, 256, 0, stream>>>(G, A, H);
    w_kernel<<<512, 256, 0, stream>>>(A, H, Wm);
    aty_kernel<<<dim3(64, 8), 256, 0, stream>>>(A, Y, AtY);

    dim3 ig(NVOX / 128, NATOMS / 64);     // (32, 8) = 256 blocks
    // iter 1: v0 = 0 -> t = AtY, v1 = x1, stored in vA
    admm_iter<1, 0><<<ig, 512, 0, stream>>>(Wm, AtY, vA, vA, nullptr);
    // iters 2..29 ping-pong: v_k lives in vA when k odd, vB when k even
    for (int it = 2; it <= NITER - 1; ++it) {
        float* in  = (it % 2 == 0) ? vA : vB;
        float* ovr = (it % 2 == 0) ? vB : vA;
        admm_iter<0, 0><<<ig, 512, 0, stream>>>(Wm, AtY, in, ovr, nullptr);
    }
    // iter 30: reads v29 (vA), writes x transposed to d_out
    admm_iter<0, 1><<<ig, 512, 0, stream>>>(Wm, AtY, vA, nullptr, (float*)d_out);
}

// Round 2
// 1690.268 us; speedup vs baseline: 4.6696x; 4.6696x over previous
//
#include <hip/hip_runtime.h>
#include <hip/hip_bf16.h>

// Problem constants (from reference setup_inputs)
#define NVOX   4096   // B voxels
#define NMEAS  256    // M measurements
#define NATOMS 512    // K atoms
#define NITER  30

// g(v) = relu(v-0.1) - min(v,0.1)   (z - u collapsed through v = x + u)
__device__ __forceinline__ float g_of(float v) {
    return fmaxf(v - 0.1f, 0.0f) - fminf(v, 0.1f);
}

// ---------------------------------------------------------------------------
// K0: G = I + A * A^T   (A is [256][512] row-major, G [256][256])
// ---------------------------------------------------------------------------
__global__ __launch_bounds__(256) void g_kernel(const float* __restrict__ A,
                                                float* __restrict__ G) {
    __shared__ float arow[NATOMS];
    int i = blockIdx.x;
    for (int k = threadIdx.x; k < NATOMS; k += 256) arow[k] = A[i * NATOMS + k];
    __syncthreads();
    int j = threadIdx.x;
    const float* aj = A + j * NATOMS;
    float s = (i == j) ? 1.0f : 0.0f;
#pragma unroll 8
    for (int k = 0; k < NATOMS; ++k) s += arow[k] * aj[k];
    G[i * NMEAS + j] = s;
}

// ---------------------------------------------------------------------------
// K1: in-place inverse of SPD G (256x256) via the symmetric SWEEP operator.
// Matrix stays symmetric every step -> pivot row == pivot column, so ALL
// register indexing is compile-time (no scratch spill; cf. rule #20).
// Sweeping all pivots yields -G^{-1}; we negate on the final store.
// 1024 threads, thread t = cb*32+rb owns the 8x8 block (rows 8rb+i, cols 8cb+j).
// ---------------------------------------------------------------------------
__global__ __launch_bounds__(1024) void sweep_inverse(float* __restrict__ M) {
    __shared__ float s_dn[NMEAS];   // pivot column, indexed by row (uniform reads)
    __shared__ float s_dt[NMEAS];   // strided layout s_dt[i*32+rb] (conflict-free per-lane reads)
    int t = threadIdx.x;
    int rb = t & 31;                // row-block (varies per lane)
    int cb = t >> 5;                // col-block (2 values per wave)
    float vals[8][8];
#pragma unroll
    for (int i = 0; i < 8; ++i) {
        const float* row = &M[(8 * rb + i) * NMEAS + 8 * cb];
        float4 a = *(const float4*)row;
        float4 b = *(const float4*)(row + 4);
        vals[i][0] = a.x; vals[i][1] = a.y; vals[i][2] = a.z; vals[i][3] = a.w;
        vals[i][4] = b.x; vals[i][5] = b.y; vals[i][6] = b.z; vals[i][7] = b.w;
    }

#pragma unroll 1
    for (int p = 0; p < NMEAS; ++p) {
        int pb = p >> 3, pi = p & 7;
        __syncthreads();            // protect s_dn/s_dt from previous iteration's readers
        if (cb == pb) {             // one wave (32 lanes) publishes pivot column
#pragma unroll
            for (int i = 0; i < 8; ++i) {
                float v = vals[i][0];
#pragma unroll
                for (int j = 1; j < 8; ++j) if (pi == j) v = vals[i][j];  // pi uniform -> cheap select
                s_dn[8 * rb + i] = v;
                s_dt[i * 32 + rb] = v;
            }
        }
        __syncthreads();
        float d   = s_dn[p];
        float inv = 1.0f / d;       // pivots >= 1 for G = I + AA^T (SPD)
        float rv[8], cv[8];
#pragma unroll
        for (int i = 0; i < 8; ++i) rv[i] = s_dt[i * 32 + rb];        // a_{row,p}
#pragma unroll
        for (int j = 0; j < 8; ++j) cv[j] = s_dn[8 * cb + j] * inv;   // a_{p,col}/d
        // generic rank-1 update; zeroes pivot row/col/elem automatically
#pragma unroll
        for (int i = 0; i < 8; ++i)
#pragma unroll
            for (int j = 0; j < 8; ++j) vals[i][j] -= rv[i] * cv[j];
        // fixup: pivot row  a_pj <- a_pj/d
        if (rb == pb) {
#pragma unroll
            for (int i = 0; i < 8; ++i) if (pi == i) {
#pragma unroll
                for (int j = 0; j < 8; ++j) vals[i][j] = cv[j];
            }
        }
        // fixup: pivot col  a_ip <- a_ip/d ; pivot elem <- -1/d
        if (cb == pb) {
#pragma unroll
            for (int j = 0; j < 8; ++j) if (pi == j) {
#pragma unroll
                for (int i = 0; i < 8; ++i)
                    vals[i][j] = (rb == pb && pi == i) ? -inv : rv[i] * inv;
            }
        }
    }
    // sweep(all) == -G^{-1}  ->  negate on store
#pragma unroll
    for (int i = 0; i < 8; ++i)
#pragma unroll
        for (int j = 0; j < 8; ++j)
            M[(8 * rb + i) * NMEAS + 8 * cb + j] = -vals[i][j];
}

// ---------------------------------------------------------------------------
// K2: H = Ginv @ A   ([256][256] @ [256][512] -> [256][512])
// ---------------------------------------------------------------------------
__global__ __launch_bounds__(256) void h_kernel(const float* __restrict__ Gi,
                                                const float* __restrict__ A,
                                                float* __restrict__ H) {
    __shared__ float grow[NMEAS];
    int i = blockIdx.x;
    grow[threadIdx.x] = Gi[i * NMEAS + threadIdx.x];
    __syncthreads();
    int k0 = threadIdx.x;
    float s0 = 0.f, s1 = 0.f;
#pragma unroll 4
    for (int j = 0; j < NMEAS; ++j) {
        float g = grow[j];
        s0 += g * A[j * NATOMS + k0];
        s1 += g * A[j * NATOMS + k0 + 256];
    }
    H[i * NATOMS + k0] = s0;
    H[i * NATOMS + k0 + 256] = s1;
}

// ---------------------------------------------------------------------------
// K3: W = I - A^T @ H   ([512][256] @ [256][512] -> [512][512])
// ---------------------------------------------------------------------------
__global__ __launch_bounds__(256) void w_kernel(const float* __restrict__ A,
                                                const float* __restrict__ H,
                                                float* __restrict__ W) {
    __shared__ float acol[NMEAS];
    int p = blockIdx.x;
    acol[threadIdx.x] = A[threadIdx.x * NATOMS + p];
    __syncthreads();
    int q0 = threadIdx.x;
    float s0 = 0.f, s1 = 0.f;
#pragma unroll 4
    for (int m = 0; m < NMEAS; ++m) {
        float a = acol[m];
        s0 += a * H[m * NATOMS + q0];
        s1 += a * H[m * NATOMS + q0 + 256];
    }
    W[p * NATOMS + q0]       = ((p == q0)       ? 1.0f : 0.0f) - s0;
    W[p * NATOMS + q0 + 256] = ((p == q0 + 256) ? 1.0f : 0.0f) - s1;
}

// ---------------------------------------------------------------------------
// K4: AtY[k][b] = sum_m A[m][k] * Y[b][m]   -> [512][4096]
// tiled 64(k) x 64(b), K-chunks of 64 over m
// ---------------------------------------------------------------------------
__global__ __launch_bounds__(256) void aty_kernel(const float* __restrict__ A,
                                                  const float* __restrict__ Y,
                                                  float* __restrict__ AtY) {
    __shared__ __align__(16) float At[64][65];  // [m][k]
    __shared__ __align__(16) float Yt[64][65];  // [m][b]
    int b0 = blockIdx.x * 64, k0 = blockIdx.y * 64;
    int t = threadIdx.x, tx = t & 15, ty = t >> 4;
    float acc[4][4] = {};
    for (int m0 = 0; m0 < NMEAS; m0 += 64) {
        __syncthreads();
        {
            int kk = t & 63, mr = t >> 6;
#pragma unroll
            for (int p = 0; p < 16; ++p)
                At[mr + 4 * p][kk] = A[(m0 + mr + 4 * p) * NATOMS + k0 + kk];
            int mm = t & 63, br = t >> 6;
#pragma unroll
            for (int p = 0; p < 16; ++p)
                Yt[mm][br + 4 * p] = Y[(b0 + br + 4 * p) * NMEAS + m0 + mm];
        }
        __syncthreads();
#pragma unroll 4
        for (int m = 0; m < 64; ++m) {
            float av[4], yv[4];
#pragma unroll
            for (int i = 0; i < 4; ++i) av[i] = At[m][ty * 4 + i];
#pragma unroll
            for (int j = 0; j < 4; ++j) yv[j] = Yt[m][tx * 4 + j];
#pragma unroll
            for (int i = 0; i < 4; ++i)
#pragma unroll
                for (int j = 0; j < 4; ++j) acc[i][j] += av[i] * yv[j];
        }
    }
#pragma unroll
    for (int i = 0; i < 4; ++i) {
        int k = k0 + ty * 4 + i;
#pragma unroll
        for (int j = 0; j < 4; ++j)
            AtY[k * NVOX + b0 + tx * 4 + j] = acc[i][j];
    }
}

// ---------------------------------------------------------------------------
// K5: one ADMM iteration, fused:  x = W @ (AtY + g(vin)),
//     vout = x + min(vin, 0.1)     (or out[b][k] = x on LAST)
// C[512][4096] = W[512][512] @ T[512][4096], BM=64 BN=128 BK=32, 512 thr
// ---------------------------------------------------------------------------
template <int FIRST, int LAST>
__global__ __launch_bounds__(512) void admm_iter(const float* __restrict__ W,
                                                 const float* __restrict__ AtY,
                                                 const float* __restrict__ vin,
                                                 float* __restrict__ vout,
                                                 float* __restrict__ out) {
    __shared__ __align__(16) float Ws[64][33];
    __shared__ __align__(16) float Ts[32][132];
    int t = threadIdx.x;
    int tx = t & 31, ty = t >> 5;          // tx: n quad, ty: m quad
    int n0 = blockIdx.x * 128, m0 = blockIdx.y * 64;
    float acc[4][4] = {};

    for (int k0 = 0; k0 < NATOMS; k0 += 32) {
        __syncthreads();
        {   // stage W tile 64x32 (row-major, pitch 33)
            int c = t & 31, r4 = t >> 5;
#pragma unroll
            for (int p = 0; p < 4; ++p)
                Ws[r4 + 16 * p][c] = W[(m0 + r4 + 16 * p) * NATOMS + k0 + c];
            // stage T tile 32x128, computing t = AtY + g(v) on the fly
            int cc = t & 127, rr = t >> 7;
#pragma unroll
            for (int p = 0; p < 8; ++p) {
                int row = rr + 4 * p;
                int gi = (k0 + row) * NVOX + n0 + cc;
                float a = AtY[gi];
                if (!FIRST) a += g_of(vin[gi]);
                Ts[row][cc] = a;
            }
        }
        __syncthreads();
#pragma unroll 8
        for (int kk = 0; kk < 32; ++kk) {
            float4 tv = *(const float4*)&Ts[kk][tx * 4];
#pragma unroll
            for (int i = 0; i < 4; ++i) {
                float wv = Ws[ty * 4 + i][kk];
                acc[i][0] += wv * tv.x;
                acc[i][1] += wv * tv.y;
                acc[i][2] += wv * tv.z;
                acc[i][3] += wv * tv.w;
            }
        }
    }

    int n = n0 + tx * 4;
#pragma unroll
    for (int i = 0; i < 4; ++i) {
        int m = m0 + ty * 4 + i;
        if (LAST) {
            // final x written transposed: out[b][k] = x[k][b]
#pragma unroll
            for (int j = 0; j < 4; ++j) out[(n + j) * NATOMS + m] = acc[i][j];
        } else {
            float4 res;
            if (!FIRST) {
                float4 v = *(const float4*)&vin[m * NVOX + n];
                res.x = acc[i][0] + fminf(v.x, 0.1f);
                res.y = acc[i][1] + fminf(v.y, 0.1f);
                res.z = acc[i][2] + fminf(v.z, 0.1f);
                res.w = acc[i][3] + fminf(v.w, 0.1f);
            } else {
                res.x = acc[i][0]; res.y = acc[i][1];
                res.z = acc[i][2]; res.w = acc[i][3];
            }
            *(float4*)&vout[m * NVOX + n] = res;
        }
    }
}

// ---------------------------------------------------------------------------
extern "C" void kernel_launch(void* const* d_in, const int* in_sizes, int n_in,
                              void* d_out, int out_size, void* d_ws, size_t ws_size,
                              hipStream_t stream) {
    const float* Y = (const float*)d_in[0];   // [4096][256]
    const float* A = (const float*)d_in[1];   // [256][512]
    // d_in[2] = max_iter (=30, hardcoded; device-side scalar not host-readable)

    float* ws = (float*)d_ws;
    float* G   = ws;                      // 256*256      = 65536
    float* H   = ws + 65536;              // 256*512      = 131072
    float* Wm  = ws + 196608;             // 512*512      = 262144
    float* AtY = ws + 458752;             // 512*4096     = 2097152
    float* vA  = ws + 2555904;            // 512*4096     = 2097152
    float* vB  = (float*)d_out;           // scratch for even iterations

    g_kernel<<<256, 256, 0, stream>>>(A, G);
    sweep_inverse<<<1, 1024, 0, stream>>>(G);
    h_kernel<<<256, 256, 0, stream>>>(G, A, H);
    w_kernel<<<512, 256, 0, stream>>>(A, H, Wm);
    aty_kernel<<<dim3(64, 8), 256, 0, stream>>>(A, Y, AtY);

    dim3 ig(NVOX / 128, NATOMS / 64);     // (32, 8) = 256 blocks
    // iter 1: v0 = 0 -> t = AtY, v1 = x1, stored in vA
    admm_iter<1, 0><<<ig, 512, 0, stream>>>(Wm, AtY, vA, vA, nullptr);
    // iters 2..29 ping-pong: v_k lives in vA when k odd, vB when k even
    for (int it = 2; it <= NITER - 1; ++it) {
        float* in  = (it % 2 == 0) ? vA : vB;
        float* ovr = (it % 2 == 0) ? vB : vA;
        admm_iter<0, 0><<<ig, 512, 0, stream>>>(Wm, AtY, in, ovr, nullptr);
    }
    // iter 30: reads v29 (vA), writes x transposed to d_out
    admm_iter<0, 1><<<ig, 512, 0, stream>>>(Wm, AtY, vA, nullptr, (float*)d_out);
}

// Round 5
// 1118.330 us; speedup vs baseline: 7.0578x; 1.5114x over previous
//
#include <hip/hip_runtime.h>

// Problem constants (from reference setup_inputs)
#define NVOX   4096   // B voxels
#define NMEAS  256    // M measurements
#define NATOMS 512    // K atoms
#define NITER  30

typedef __attribute__((ext_vector_type(8))) short s8v;   // 8 bf16 (4 VGPR) MFMA frag
typedef __attribute__((ext_vector_type(4))) short s4v;
typedef __attribute__((ext_vector_type(4))) float f32x4;

// bf16 round-to-nearest-even split helpers (no NaN/Inf in this problem)
__device__ __forceinline__ unsigned short f2bf(float x) {
    unsigned u = __builtin_bit_cast(unsigned, x);
    u += 0x7fff + ((u >> 16) & 1);
    return (unsigned short)(u >> 16);
}
__device__ __forceinline__ float bf2f(unsigned short b) {
    unsigned u = ((unsigned)b) << 16;
    return __builtin_bit_cast(float, u);
}
// g(v) = (z - u) collapsed through v = x + u :  relu(v-0.1) - min(v,0.1)
__device__ __forceinline__ float g_of(float v) {
    return fmaxf(v - 0.1f, 0.0f) - fminf(v, 0.1f);
}

// ---------------------------------------------------------------------------
// K0: G = I + A*A^T in fp64 (Gd) + fp32 copy (Gf) for the sweep
// ---------------------------------------------------------------------------
__global__ __launch_bounds__(256) void g_kernel_d(const float* __restrict__ A,
                                                  double* __restrict__ Gd,
                                                  float* __restrict__ Gf) {
    __shared__ float arow[NATOMS];
    int i = blockIdx.x;
    for (int k = threadIdx.x; k < NATOMS; k += 256) arow[k] = A[i * NATOMS + k];
    __syncthreads();
    int j = threadIdx.x;
    const float* aj = A + j * NATOMS;
    double s = (i == j) ? 1.0 : 0.0;
#pragma unroll 4
    for (int k = 0; k < NATOMS; ++k) s += (double)arow[k] * (double)aj[k];
    Gd[i * NMEAS + j] = s;
    Gf[i * NMEAS + j] = (float)s;
}

// ---------------------------------------------------------------------------
// K1: SPD inverse of Gf (256x256) via symmetric SWEEP operator (src -> dst).
// All register indexing compile-time (rule #20). sweep(all pivots) = -G^{-1}.
// (round-2 proven version, unchanged)
// ---------------------------------------------------------------------------
__global__ __launch_bounds__(1024) void sweep_inverse(const float* __restrict__ src,
                                                      float* __restrict__ dst) {
    __shared__ float s_dn[NMEAS];
    __shared__ float s_dt[NMEAS];
    int t = threadIdx.x;
    int rb = t & 31;
    int cb = t >> 5;
    float vals[8][8];
#pragma unroll
    for (int i = 0; i < 8; ++i) {
        const float* row = &src[(8 * rb + i) * NMEAS + 8 * cb];
        float4 a = *(const float4*)row;
        float4 b = *(const float4*)(row + 4);
        vals[i][0] = a.x; vals[i][1] = a.y; vals[i][2] = a.z; vals[i][3] = a.w;
        vals[i][4] = b.x; vals[i][5] = b.y; vals[i][6] = b.z; vals[i][7] = b.w;
    }
#pragma unroll 1
    for (int p = 0; p < NMEAS; ++p) {
        int pb = p >> 3, pi = p & 7;
        __syncthreads();
        if (cb == pb) {
#pragma unroll
            for (int i = 0; i < 8; ++i) {
                float v = vals[i][0];
#pragma unroll
                for (int j = 1; j < 8; ++j) if (pi == j) v = vals[i][j];
                s_dn[8 * rb + i] = v;
                s_dt[i * 32 + rb] = v;
            }
        }
        __syncthreads();
        float d   = s_dn[p];
        float inv = 1.0f / d;
        float rv[8], cv[8];
#pragma unroll
        for (int i = 0; i < 8; ++i) rv[i] = s_dt[i * 32 + rb];
#pragma unroll
        for (int j = 0; j < 8; ++j) cv[j] = s_dn[8 * cb + j] * inv;
#pragma unroll
        for (int i = 0; i < 8; ++i)
#pragma unroll
            for (int j = 0; j < 8; ++j) vals[i][j] -= rv[i] * cv[j];
        if (rb == pb) {
#pragma unroll
            for (int i = 0; i < 8; ++i) if (pi == i) {
#pragma unroll
                for (int j = 0; j < 8; ++j) vals[i][j] = cv[j];
            }
        }
        if (cb == pb) {
#pragma unroll
            for (int j = 0; j < 8; ++j) if (pi == j) {
#pragma unroll
                for (int i = 0; i < 8; ++i)
                    vals[i][j] = (rb == pb && pi == i) ? -inv : rv[i] * inv;
            }
        }
    }
#pragma unroll
    for (int i = 0; i < 8; ++i)
#pragma unroll
        for (int j = 0; j < 8; ++j)
            dst[(8 * rb + i) * NMEAS + 8 * cb + j] = -vals[i][j];
}

// ---------------------------------------------------------------------------
// fp64 Newton refinement:  P = Gd @ X ;  Xn = 2X - X @ P   (X input fp32 or fp64)
// fp32 Newton was the round-3/4 bug: computing G@X in fp32 has cancellation
// noise ~cond(G)*eps32 ~ 4e-3/entry which the update injects into X. fp64
// makes that 7e-12 — Newton then truly squares the sweep's residual.
// ---------------------------------------------------------------------------
template <typename TB>
__global__ __launch_bounds__(256) void mm_gd(const double* __restrict__ Gd,
                                             const TB* __restrict__ X,
                                             double* __restrict__ P) {
    __shared__ __align__(16) double row[NMEAS];
    int i = blockIdx.x;
    row[threadIdx.x] = Gd[i * NMEAS + threadIdx.x];
    __syncthreads();
    int j = threadIdx.x;
    double s = 0.0;
#pragma unroll 4
    for (int k = 0; k < NMEAS; ++k) s += row[k] * (double)X[k * NMEAS + j];
    P[i * NMEAS + j] = s;
}

template <typename TB>
__global__ __launch_bounds__(256) void upd_newton(const TB* __restrict__ X,
                                                  const double* __restrict__ P,
                                                  double* __restrict__ Xn) {
    __shared__ __align__(16) double row[NMEAS];
    int i = blockIdx.x;
    row[threadIdx.x] = (double)X[i * NMEAS + threadIdx.x];
    __syncthreads();
    int j = threadIdx.x;
    double s = 0.0;
#pragma unroll 4
    for (int k = 0; k < NMEAS; ++k) s += row[k] * P[k * NMEAS + j];
    Xn[i * NMEAS + j] = 2.0 * row[j] - s;
}

// ---------------------------------------------------------------------------
// K2: Hd = X2d @ A   (fp64 [256][256] @ fp32 [256][512] -> fp64 [256][512])
// ---------------------------------------------------------------------------
__global__ __launch_bounds__(256) void h_kernel_d(const double* __restrict__ Gi,
                                                  const float* __restrict__ A,
                                                  double* __restrict__ H) {
    __shared__ __align__(16) double grow[NMEAS];
    int i = blockIdx.x;
    grow[threadIdx.x] = Gi[i * NMEAS + threadIdx.x];
    __syncthreads();
    int k0 = threadIdx.x;
    double s0 = 0.0, s1 = 0.0;
#pragma unroll 4
    for (int j = 0; j < NMEAS; ++j) {
        double g = grow[j];
        s0 += g * (double)A[j * NATOMS + k0];
        s1 += g * (double)A[j * NATOMS + k0 + 256];
    }
    H[i * NATOMS + k0] = s0;
    H[i * NATOMS + k0 + 256] = s1;
}

// ---------------------------------------------------------------------------
// K3: W = I - A^T @ Hd  (fp64 accumulate), stored as bf16 hi/lo split
// ---------------------------------------------------------------------------
__global__ __launch_bounds__(256) void w_kernel_d(const float* __restrict__ A,
                                                  const double* __restrict__ H,
                                                  unsigned short* __restrict__ Whg,
                                                  unsigned short* __restrict__ Wlg) {
    __shared__ __align__(16) double acol[NMEAS];
    int p = blockIdx.x;
    acol[threadIdx.x] = (double)A[threadIdx.x * NATOMS + p];
    __syncthreads();
    int q0 = threadIdx.x;
    double s0 = 0.0, s1 = 0.0;
#pragma unroll 4
    for (int m = 0; m < NMEAS; ++m) {
        double a = acol[m];
        s0 += a * H[m * NATOMS + q0];
        s1 += a * H[m * NATOMS + q0 + 256];
    }
    double w0 = ((p == q0)       ? 1.0 : 0.0) - s0;
    double w1 = ((p == q0 + 256) ? 1.0 : 0.0) - s1;
    unsigned short h0 = f2bf((float)w0), h1 = f2bf((float)w1);
    Whg[p * NATOMS + q0]       = h0;
    Wlg[p * NATOMS + q0]       = f2bf((float)(w0 - (double)bf2f(h0)));
    Whg[p * NATOMS + q0 + 256] = h1;
    Wlg[p * NATOMS + q0 + 256] = f2bf((float)(w1 - (double)bf2f(h1)));
}

// ---------------------------------------------------------------------------
// K4: Delta0 = AtY (= t_1, since t_0 = 0), stored split bf16 hi/lo,
//     TRANSPOSED to [4096 voxels][512 atoms] for k-contiguous staging.
// AtY[k][b] = sum_m A[m][k] * Y[b][m]
// ---------------------------------------------------------------------------
__global__ __launch_bounds__(256) void aty_kernel(const float* __restrict__ A,
                                                  const float* __restrict__ Y,
                                                  unsigned short* __restrict__ Dh0,
                                                  unsigned short* __restrict__ Dl0) {
    __shared__ __align__(16) float At[64][65];
    __shared__ __align__(16) float Yt[64][65];
    int b0 = blockIdx.x * 64, k0 = blockIdx.y * 64;
    int t = threadIdx.x, tx = t & 15, ty = t >> 4;
    float acc[4][4] = {};
    for (int m0 = 0; m0 < NMEAS; m0 += 64) {
        __syncthreads();
        {
            int kk = t & 63, mr = t >> 6;
#pragma unroll
            for (int p = 0; p < 16; ++p)
                At[mr + 4 * p][kk] = A[(m0 + mr + 4 * p) * NATOMS + k0 + kk];
            int mm = t & 63, br = t >> 6;
#pragma unroll
            for (int p = 0; p < 16; ++p)
                Yt[mm][br + 4 * p] = Y[(b0 + br + 4 * p) * NMEAS + m0 + mm];
        }
        __syncthreads();
#pragma unroll 4
        for (int m = 0; m < 64; ++m) {
            float av[4], yv[4];
#pragma unroll
            for (int i = 0; i < 4; ++i) av[i] = At[m][ty * 4 + i];
#pragma unroll
            for (int j = 0; j < 4; ++j) yv[j] = Yt[m][tx * 4 + j];
#pragma unroll
            for (int i = 0; i < 4; ++i)
#pragma unroll
                for (int j = 0; j < 4; ++j) acc[i][j] += av[i] * yv[j];
        }
    }
#pragma unroll
    for (int j = 0; j < 4; ++j) {
        int b = b0 + tx * 4 + j;
        s4v h4, l4;
#pragma unroll
        for (int i = 0; i < 4; ++i) {
            float f = acc[i][j];
            unsigned short h = f2bf(f);
            h4[i] = (short)h;
            l4[i] = (short)f2bf(f - bf2f(h));
        }
        *(s4v*)&Dh0[(long)b * NATOMS + k0 + ty * 4] = h4;
        *(s4v*)&Dl0[(long)b * NATOMS + k0 + ty * 4] = l4;
    }
}

// ---------------------------------------------------------------------------
// K5: one ADMM iteration, DELTA form (bf16-split MFMA, all 4 terms):
//   dx = W @ Delta_in            (Delta decays with k -> split error decays)
//   x_k = x_{k-1} + dx ;  v_k = x_k + min(v_{k-1}, 0.1)
//   Delta_out = g(v_k) - g(v_{k-1})    -> split bf16, transposed [n][k]
// LAST: out[b][k] = x_{k-1} + dx  (transposed fp32 write)
// Tile: BM=64 x BN=128, BK=32, 256 thr (4 waves), mfma_f32_16x16x32_bf16.
// (round-4 machinery, verified correct by the identical-absmax evidence)
// ---------------------------------------------------------------------------
template <int FIRST, int LAST>
__global__ __launch_bounds__(256) void admm_delta(
        const unsigned short* __restrict__ Whg,
        const unsigned short* __restrict__ Wlg,
        const unsigned short* __restrict__ Dhg,
        const unsigned short* __restrict__ Dlg,
        float* __restrict__ xbuf,            // fp32 x [512][4096], in-place
        float* __restrict__ vbuf,            // fp32 v [512][4096], in-place (d_out)
        unsigned short* __restrict__ DhOut,
        unsigned short* __restrict__ DlOut,
        float* __restrict__ out) {
    __shared__ __align__(16) char smem[61440];
    unsigned short* Whs = (unsigned short*)smem;      // [2][64*40]
    unsigned short* Wls = Whs + 2 * 64 * 40;          // [2][64*40]
    unsigned short* Dhs = Wls + 2 * 64 * 40;          // [2][128*40]
    unsigned short* Dls = Dhs + 2 * 128 * 40;         // [2][128*40]

    const int t = threadIdx.x;
    const int lane = t & 63, wv = t >> 6;
    const int ln = lane & 15, kg = lane >> 4;
    const int n0 = blockIdx.x * 128, m0 = blockIdx.y * 64;

    const int wm = t >> 2, wslot = t & 3;
    const int tn = t >> 2, tslot = t & 3;

    f32x4 acc[4][2] = {};
    s8v rwh, rwl, rth0, rth1, rtl0, rtl1;

#define GLOAD(kc)                                                                \
    {                                                                            \
        long ko = (long)(kc)*32;                                                 \
        rwh  = *(const s8v*)&Whg[(long)(m0 + wm) * NATOMS + ko + wslot * 8];     \
        rwl  = *(const s8v*)&Wlg[(long)(m0 + wm) * NATOMS + ko + wslot * 8];     \
        rth0 = *(const s8v*)&Dhg[(long)(n0 + tn) * NATOMS + ko + tslot * 8];     \
        rth1 = *(const s8v*)&Dhg[(long)(n0 + 64 + tn) * NATOMS + ko + tslot * 8];\
        rtl0 = *(const s8v*)&Dlg[(long)(n0 + tn) * NATOMS + ko + tslot * 8];     \
        rtl1 = *(const s8v*)&Dlg[(long)(n0 + 64 + tn) * NATOMS + ko + tslot * 8];\
    }
#define DSWRITE(b)                                                  \
    {                                                               \
        *(s8v*)&Whs[(b)*2560 + wm * 40 + wslot * 8] = rwh;          \
        *(s8v*)&Wls[(b)*2560 + wm * 40 + wslot * 8] = rwl;          \
        *(s8v*)&Dhs[(b)*5120 + tn * 40 + tslot * 8] = rth0;         \
        *(s8v*)&Dhs[(b)*5120 + (64 + tn) * 40 + tslot * 8] = rth1;  \
        *(s8v*)&Dls[(b)*5120 + tn * 40 + tslot * 8] = rtl0;         \
        *(s8v*)&Dls[(b)*5120 + (64 + tn) * 40 + tslot * 8] = rtl1;  \
    }

    GLOAD(0);
    DSWRITE(0);
#pragma unroll 1
    for (int c = 0; c < 16; ++c) {
        if (c < 15) GLOAD(c + 1);
        __syncthreads();
        const int b = c & 1;
        const unsigned short* wh = &Whs[b * 2560];
        const unsigned short* wl = &Wls[b * 2560];
        const unsigned short* dh = &Dhs[b * 5120];
        const unsigned short* dl = &Dls[b * 5120];
        s8v ah[4], al[4], bh[2], bl[2];
#pragma unroll
        for (int mi = 0; mi < 4; ++mi) {
            ah[mi] = *(const s8v*)&wh[(mi * 16 + ln) * 40 + kg * 8];
            al[mi] = *(const s8v*)&wl[(mi * 16 + ln) * 40 + kg * 8];
        }
#pragma unroll
        for (int ni = 0; ni < 2; ++ni) {
            int r = wv * 32 + ni * 16 + ln;
            bh[ni] = *(const s8v*)&dh[r * 40 + kg * 8];
            bl[ni] = *(const s8v*)&dl[r * 40 + kg * 8];
        }
#pragma unroll
        for (int mi = 0; mi < 4; ++mi)
#pragma unroll
            for (int ni = 0; ni < 2; ++ni) {
                acc[mi][ni] = __builtin_amdgcn_mfma_f32_16x16x32_bf16(ah[mi], bh[ni], acc[mi][ni], 0, 0, 0);
                acc[mi][ni] = __builtin_amdgcn_mfma_f32_16x16x32_bf16(ah[mi], bl[ni], acc[mi][ni], 0, 0, 0);
                acc[mi][ni] = __builtin_amdgcn_mfma_f32_16x16x32_bf16(al[mi], bh[ni], acc[mi][ni], 0, 0, 0);
                acc[mi][ni] = __builtin_amdgcn_mfma_f32_16x16x32_bf16(al[mi], bl[ni], acc[mi][ni], 0, 0, 0);
            }
        if (c < 15) DSWRITE((c + 1) & 1);
    }
#undef GLOAD
#undef DSWRITE

    __syncthreads();                        // staging LDS dead; reuse as xT [128][68] f32
    float* xT = (float*)smem;

    if (!LAST) {
#pragma unroll
        for (int mi = 0; mi < 4; ++mi)
#pragma unroll
            for (int ni = 0; ni < 2; ++ni) {
                int nn = n0 + wv * 32 + ni * 16 + ln;
                f32x4 dlt;
#pragma unroll
                for (int j = 0; j < 4; ++j) {
                    int m = m0 + mi * 16 + kg * 4 + j;
                    long idx = (long)m * NVOX + nn;
                    float dx = acc[mi][ni][j];
                    float xn, vn, gold;
                    if (FIRST) {
                        xn = dx; vn = xn; gold = 0.0f;   // x0=0, u0=0, v0=0
                    } else {
                        xn = xbuf[idx] + dx;
                        float vp = vbuf[idx];
                        vn = xn + fminf(vp, 0.1f);
                        gold = g_of(vp);
                    }
                    xbuf[idx] = xn;
                    vbuf[idx] = vn;
                    dlt[j] = g_of(vn) - gold;
                }
                int nl = wv * 32 + ni * 16 + ln;
                int ml = mi * 16 + kg * 4;
                *(f32x4*)&xT[nl * 68 + ml] = dlt;
            }
        __syncthreads();
        int nl = t >> 1, seg = t & 1;
#pragma unroll
        for (int q8 = 0; q8 < 4; ++q8) {
            s8v hv, lv;
#pragma unroll
            for (int e = 0; e < 8; ++e) {
                float f = xT[nl * 68 + seg * 32 + q8 * 8 + e];
                unsigned short h = f2bf(f);
                hv[e] = (short)h;
                lv[e] = (short)f2bf(f - bf2f(h));
            }
            *(s8v*)&DhOut[(long)(n0 + nl) * NATOMS + m0 + seg * 32 + q8 * 8] = hv;
            *(s8v*)&DlOut[(long)(n0 + nl) * NATOMS + m0 + seg * 32 + q8 * 8] = lv;
        }
    } else {
        // LAST: out[b][k] = x_{k-1}[k][b] + dx  (transposed fp32 write)
#pragma unroll
        for (int mi = 0; mi < 4; ++mi)
#pragma unroll
            for (int ni = 0; ni < 2; ++ni) {
                int nn = n0 + wv * 32 + ni * 16 + ln;
                f32x4 tv;
#pragma unroll
                for (int j = 0; j < 4; ++j) {
                    int m = m0 + mi * 16 + kg * 4 + j;
                    tv[j] = xbuf[(long)m * NVOX + nn] + acc[mi][ni][j];
                }
                int nl = wv * 32 + ni * 16 + ln;
                int ml = mi * 16 + kg * 4;
                *(f32x4*)&xT[nl * 68 + ml] = tv;
            }
        __syncthreads();
        int nl = t >> 1, seg = t & 1;
#pragma unroll
        for (int q = 0; q < 8; ++q) {
            f32x4 v = *(const f32x4*)&xT[nl * 68 + seg * 32 + q * 4];
            *(f32x4*)&out[(long)(n0 + nl) * NATOMS + m0 + seg * 32 + q * 4] = v;
        }
    }
}

// ---------------------------------------------------------------------------
extern "C" void kernel_launch(void* const* d_in, const int* in_sizes, int n_in,
                              void* d_out, int out_size, void* d_ws, size_t ws_size,
                              hipStream_t stream) {
    const float* Y = (const float*)d_in[0];   // [4096][256]
    const float* A = (const float*)d_in[1];   // [256][512]

    // ws layout (float units), lifetime-checked overlays; total 6946816 floats
    // = 26.5 MiB == round-3/4 proven footprint.
    float* ws = (float*)d_ws;
    double* Gd  = (double*)(ws + 0);        // [0,131072)       dead after step 5
    float*  Gf  = ws + 131072;              // [131072,196608)  dead after sweep
    float*  X0f = ws + 196608;              // [196608,262144)  dead after step 4
    double* X1d = (double*)(ws + 262144);   // [262144,393216)  dead after step 6
    double* Pd  = (double*)(ws + 393216);   // [393216,524288)  dead after step 6
    double* X2d = (double*)(ws + 131072);   // overlays Gf+X0f (both dead)
    double* Hd  = (double*)(ws + 393216);   // [393216,655360) overlays Pd (dead)
    float*  xbuf = ws + 655360;             // [655360,2752512) fp32 x state
    unsigned short* Whg = (unsigned short*)(ws + 0);        // overlays Gd (dead)
    unsigned short* Wlg = (unsigned short*)(ws + 131072);   // overlays X2d (dead after h)
    unsigned short* DAh = (unsigned short*)(ws + 2752512);
    unsigned short* DAl = (unsigned short*)(ws + 3801088);
    unsigned short* DBh = (unsigned short*)(ws + 4849664);
    unsigned short* DBl = (unsigned short*)(ws + 5898240);  // end 6946816
    float* vbuf = (float*)d_out;   // v_k fp32, iters 1..29 (d_out as scratch)
    float* outp = (float*)d_out;   // final output, written by LAST iter only

    g_kernel_d<<<256, 256, 0, stream>>>(A, Gd, Gf);                 // 1
    sweep_inverse<<<1, 1024, 0, stream>>>(Gf, X0f);                 // 2
    mm_gd<float><<<256, 256, 0, stream>>>(Gd, X0f, Pd);             // 3
    upd_newton<float><<<256, 256, 0, stream>>>(X0f, Pd, X1d);       // 4
    mm_gd<double><<<256, 256, 0, stream>>>(Gd, X1d, Pd);            // 5
    upd_newton<double><<<256, 256, 0, stream>>>(X1d, Pd, X2d);      // 6
    h_kernel_d<<<256, 256, 0, stream>>>(X2d, A, Hd);                // 7
    w_kernel_d<<<512, 256, 0, stream>>>(A, Hd, Whg, Wlg);           // 8
    aty_kernel<<<dim3(64, 8), 256, 0, stream>>>(A, Y, DAh, DAl);    // 9

    dim3 ig(NVOX / 128, NATOMS / 64);  // (32, 8) = 256 blocks
    unsigned short *ch = DAh, *cl = DAl, *nh = DBh, *nl = DBl;
    // iter 1: Delta_0 = AtY; x1 = W*AtY; v1 = x1; Delta_1 = g(v1)
    admm_delta<1, 0><<<ig, 256, 0, stream>>>(Whg, Wlg, ch, cl, xbuf, vbuf, nh, nl, nullptr);
    { unsigned short* s; s = ch; ch = nh; nh = s; s = cl; cl = nl; nl = s; }
    for (int it = 2; it <= NITER - 1; ++it) {
        admm_delta<0, 0><<<ig, 256, 0, stream>>>(Whg, Wlg, ch, cl, xbuf, vbuf, nh, nl, nullptr);
        unsigned short* s; s = ch; ch = nh; nh = s; s = cl; cl = nl; nl = s;
    }
    // iter 30: x30 = x29 + W*Delta_29, written transposed to d_out
    admm_delta<0, 1><<<ig, 256, 0, stream>>>(Whg, Wlg, ch, cl, xbuf, vbuf, nullptr, nullptr, outp);
}